// Round 14
// baseline (414.581 us; speedup 1.0000x reference)
//
#include <hip/hip_runtime.h>

#define ND   2048
#define BB   16384

typedef unsigned short u16;
typedef unsigned int u32;
typedef __attribute__((ext_vector_type(8))) short short8;
typedef __attribute__((ext_vector_type(4))) float f32x4;

__device__ inline float bf2f(u16 u) {
    union { u32 i; float f; } v; v.i = ((u32)u) << 16; return v.f;
}
__device__ inline u16 f2bf(float f) {
    union { float f; u32 i; } v; v.f = f;
    u32 i = v.i + 0x7fffu + ((v.i >> 16) & 1u);
    return (u16)(i >> 16);
}
__device__ inline float seluf(float x) {
    const float sc = 1.0507009873554805f, al = 1.6732632423543772f;
    return x > 0.f ? sc * x : sc * al * expm1f(x);
}
__device__ inline short8 packbf8(float4 f0, float4 f1) {
    short8 a;
    a[0] = (short)f2bf(f0.x); a[1] = (short)f2bf(f0.y);
    a[2] = (short)f2bf(f0.z); a[3] = (short)f2bf(f0.w);
    a[4] = (short)f2bf(f1.x); a[5] = (short)f2bf(f1.y);
    a[6] = (short)f2bf(f1.z); a[7] = (short)f2bf(f1.w);
    return a;
}

// ---------------- dtype sniffer ----------------
__global__ void detectk(const void* __restrict__ demb, u32* __restrict__ flag) {
    const u16* p = (const u16*)demb;
    int tid = threadIdx.x;  // 256
    int sane = 0;
    #pragma unroll
    for (int i = 0; i < 2; i++) {
        u16 u = p[4 * tid + 2 * i];
        int e = (u >> 7) & 0xFF;
        if (u == 0 || (e >= 0x66 && e <= 0x8C)) sane++;
    }
    __shared__ int red[256];
    red[tid] = sane; __syncthreads();
    for (int o = 128; o > 0; o >>= 1) {
        if (tid < o) red[tid] += red[tid + o];
        __syncthreads();
    }
    if (tid == 0) flag[0] = (red[0] < 300) ? 1u : 0u;
}

// ---------------- canonical bf16 conversion (26 segments, one launch) -------
#define NSEG 26
struct CvtArgs { const void* src[NSEG]; int off[NSEG]; int n[NSEG]; };

__global__ __launch_bounds__(256) void cvtk(CvtArgs a, u16* __restrict__ base,
                                            const u32* __restrict__ flag) {
    int seg = blockIdx.y;
    int n = a.n[seg];
    const void* s = a.src[seg];
    u16* d = base + a.off[seg];
    bool f32 = flag[0] != 0;
    int stride = gridDim.x * blockDim.x;
    for (int i = blockIdx.x * blockDim.x + threadIdx.x; i < n; i += stride)
        d[i] = f32 ? f2bf(((const float*)s)[i]) : ((const u16*)s)[i];
}

// ---------------- small 128x128 transposes ----------------
__device__ inline void tpose_body(const u16* in, int R, int C,
                                  u16* out, int ldo, int ooff,
                                  u16 (*tile)[33]) {
    int c0 = blockIdx.x * 32, r0 = blockIdx.y * 32;
    int x = c0 + threadIdx.x;
    for (int i = threadIdx.y; i < 32; i += 8) {
        int r = r0 + i;
        tile[i][threadIdx.x] = (r < R && x < C) ? in[(size_t)r * C + x] : (u16)0;
    }
    __syncthreads();
    int rr = r0 + threadIdx.x;
    for (int i = threadIdx.y; i < 32; i += 8) {
        int cc = c0 + i;
        if (cc < C && rr < R) out[(size_t)cc * ldo + ooff + rr] = tile[threadIdx.x][i];
    }
}

__global__ void tpose_smalls(const u16* s0, const u16* s1, const u16* s2,
                             const u16* s3, const u16* s4, const u16* s5,
                             u16* W1T, u16* W2T, u16* WcTe, u16* WcTp) {
    __shared__ u16 tile[32][33];
    const u16* in; u16* out; int ldo, ooff;
    switch (blockIdx.z) {
        case 0:  in = s0; out = W1T;  ldo = 128; ooff = 0;   break;
        case 1:  in = s1; out = W2T;  ldo = 128; ooff = 0;   break;
        case 2:  in = s2; out = WcTe; ldo = 256; ooff = 0;   break;
        case 3:  in = s3; out = WcTe; ldo = 256; ooff = 128; break;
        case 4:  in = s4; out = WcTp; ldo = 256; ooff = 0;   break;
        default: in = s5; out = WcTp; ldo = 256; ooff = 128; break;
    }
    tpose_body(in, 128, 128, out, ldo, ooff, tile);
}

// ---------------- e_p adjacency transpose -> bf16 ----------------
__global__ void tposeEP(const void* __restrict__ in, u16* __restrict__ out,
                        const u32* __restrict__ flag) {
    __shared__ u16 tile[32][33];
    bool f32 = flag[0] != 0;
    int c0 = blockIdx.x * 32, r0 = blockIdx.y * 32;
    int x = c0 + threadIdx.x;
    for (int i = threadIdx.y; i < 32; i += 8) {
        int r = r0 + i;
        tile[i][threadIdx.x] = f32 ? f2bf(((const float*)in)[(size_t)r * 2048 + x])
                                   : ((const u16*)in)[(size_t)r * 2048 + x];
    }
    __syncthreads();
    int rr = r0 + threadIdx.x;
    for (int i = threadIdx.y; i < 32; i += 8)
        out[(size_t)(c0 + i) * 2048 + rr] = tile[threadIdx.x][i];
}

// ---------------- combined biases ----------------
__global__ void biasc(const u16* a0, const u16* a1, const u16* a2, u16* o0,
                      const u16* b0, const u16* b1, const u16* b2, u16* o1) {
    int t = threadIdx.x;  // 128
    o0[t] = f2bf(bf2f(a0[t]) + bf2f(a1[t]) + bf2f(a2[t]));
    o1[t] = f2bf(bf2f(b0[t]) + bf2f(b1[t]) + bf2f(b2[t]));
}

// ---------------- embedding column sums (f32) ----------------
__global__ __launch_bounds__(1024) void embsumk(const u16* __restrict__ demb,
                                                const u16* __restrict__ pemb,
                                                float* __restrict__ se,
                                                float* __restrict__ sp) {
    const u16* src = blockIdx.x ? pemb : demb;
    float* dst = blockIdx.x ? sp : se;
    int d = threadIdx.x & 127, r8 = threadIdx.x >> 7;
    float s = 0.f;
    for (int r = r8; r < 2048; r += 8)
        s += bf2f(src[(size_t)r * 128 + d]);
    __shared__ float part[8][128];
    part[r8][d] = s;
    __syncthreads();
    if (threadIdx.x < 128) {
        float t = 0.f;
        #pragma unroll
        for (int i = 0; i < 8; i++) t += part[i][threadIdx.x];
        dst[threadIdx.x] = t;
    }
}

// ---------------- ko / qs projections ----------
__global__ __launch_bounds__(128) void koqs(
    const u16* __restrict__ demb, const u16* __restrict__ pemb,
    const u16* __restrict__ Wa1d, const u16* __restrict__ ba1d,
    const u16* __restrict__ Wa1p, const u16* __restrict__ ba1p,
    float* __restrict__ ko_d, float* __restrict__ qs_d,
    float* __restrict__ ko_p, float* __restrict__ qs_p) {
    int row = blockIdx.x, m = blockIdx.y, tid = threadIdx.x;
    const u16* src; const u16* W; const u16* bias; float* out;
    switch (m) {
        case 0:  src = pemb; W = Wa1d;            bias = nullptr; out = ko_d; break;
        case 1:  src = demb; W = Wa1d + 128 * 32; bias = ba1d;    out = qs_d; break;
        case 2:  src = demb; W = Wa1p;            bias = nullptr; out = ko_p; break;
        default: src = pemb; W = Wa1p + 128 * 32; bias = ba1p;    out = qs_p; break;
    }
    __shared__ float x[128];
    __shared__ float red[128];
    x[tid] = bf2f(src[(size_t)row * 128 + tid]);
    __syncthreads();
    int a = tid & 31, part = tid >> 5;
    float s = 0.f;
    #pragma unroll
    for (int k = 0; k < 32; k++) s += x[part * 32 + k] * bf2f(W[(part * 32 + k) * 32 + a]);
    red[tid] = s;
    __syncthreads();
    if (part == 0) {
        float t = red[a] + red[a + 32] + red[a + 64] + red[a + 96];
        if (bias) t += bf2f(bias[a]);
        out[(size_t)row * 32 + a] = t;
    }
}

// ---------------- sparse fused attention/knn aggregation ----------------
// exp(s*adj) = 1 + adj*expm1(s)  (adj in {0,1}, s>=0)
//   softmax @ emb = (colsum(emb) + sum_edges expm1(s)*emb[j]) / (2048 + sum_edges expm1(s))
//   knn          = (sum_edges val*emb[j]) / (sum vals + 1e-8)
// grid (2048, 4), block 256. One row per block.
#define ECAP 512
struct SG {
    const void* adj[4];
    int adjbf[4];            // 1 = adjacency always bf16 (epT); 0 = flag decides
    const float* qs[4]; const float* ko[4];
    const u16* w2[4]; const u16* b2[4];
    const float* embsum[4];
    const u16* emb[4];
    u16* outp[4]; int coff[4];
    int mode[4];             // 0 attention, 1 knn
};

__global__ __launch_bounds__(256, 4) void sagg(SG p, const u32* __restrict__ flag) {
    __shared__ float accA[128], accB[128];
    __shared__ float qsh[32], w2sh[32];
    __shared__ float wlist[ECAP];
    __shared__ int jlist[ECAP];
    __shared__ float red[256];
    __shared__ int ecnt;
    __shared__ float wsum_sh;
    int z = blockIdx.y;
    int row = blockIdx.x;
    int tid = threadIdx.x;
    int mode = p.mode[z];
    bool f32a = (p.adjbf[z] == 0) && (flag[0] != 0);
    const float* adjf = (const float*)p.adj[z];
    const u16*   adjh = (const u16*)p.adj[z];
    if (tid < 128) { accA[tid] = 0.f; accB[tid] = 0.f; }
    if (tid == 0) ecnt = 0;
    if (mode == 0) {
        if (tid < 32) qsh[tid] = p.qs[z][(size_t)row * 32 + tid];
        else if (tid < 64) w2sh[tid - 32] = bf2f(p.w2[z][tid - 32]);
    }
    __syncthreads();
    float b2v = (mode == 0) ? bf2f(p.b2[z][0]) : 0.f;
    const float* ko = p.ko[z];
    #pragma unroll 1
    for (int c = 0; c < 8; c++) {
        int j = c * 256 + tid;
        float av = f32a ? adjf[(size_t)row * 2048 + j]
                        : bf2f(adjh[(size_t)row * 2048 + j]);
        if (av != 0.f) {
            float w;
            if (mode == 0) {
                const float4* kp = (const float4*)(ko + (size_t)j * 32);
                float s = 0.f;
                #pragma unroll
                for (int qd = 0; qd < 8; qd++) {
                    float4 kv = kp[qd];
                    s += fmaxf(qsh[qd * 4 + 0] + kv.x, 0.f) * w2sh[qd * 4 + 0];
                    s += fmaxf(qsh[qd * 4 + 1] + kv.y, 0.f) * w2sh[qd * 4 + 1];
                    s += fmaxf(qsh[qd * 4 + 2] + kv.z, 0.f) * w2sh[qd * 4 + 2];
                    s += fmaxf(qsh[qd * 4 + 3] + kv.w, 0.f) * w2sh[qd * 4 + 3];
                }
                s = fmaxf(s + b2v, 0.f);
                w = expm1f(s);
            } else {
                w = av;
            }
            int idx = atomicAdd(&ecnt, 1);
            if (idx < ECAP) { jlist[idx] = j; wlist[idx] = w; }
        }
    }
    __syncthreads();
    int E = min(ecnt, ECAP);
    // weight-sum reduction
    float ws0 = 0.f;
    if (tid < E) ws0 = wlist[tid];
    if (tid + 256 < E) ws0 += wlist[tid + 256];
    red[tid] = ws0;
    __syncthreads();
    for (int o = 128; o > 0; o >>= 1) {
        if (tid < o) red[tid] += red[tid + o];
        __syncthreads();
    }
    if (tid == 0) wsum_sh = red[0];
    // edge accumulation: half 0 takes even edges, half 1 odd
    int d = tid & 127, half = tid >> 7;
    const u16* emb = p.emb[z];
    float acc = 0.f;
    #pragma unroll 1
    for (int e = half; e < E; e += 2)
        acc += wlist[e] * bf2f(emb[(size_t)jlist[e] * 128 + d]);
    if (half == 0) accA[d] = acc; else accB[d] = acc;
    __syncthreads();
    if (tid < 128) {
        float v = accA[tid] + accB[tid];
        float denom;
        if (mode == 0) { v += p.embsum[z][tid]; denom = 2048.f + wsum_sh; }
        else denom = wsum_sh + 1e-8f;
        p.outp[z][(size_t)row * 256 + p.coff[z] + tid] = f2bf(v / denom);
    }
}

// ---------------- MFMA GEMM: canonical LDS-tiled (guide §5) -----------------
struct GD4 {
    const void* A[4]; const u16* BT[4]; u16* C[4];
    const u16* bias[4]; const float* rs[4];
    int lda[4], ldb[4], ldc[4], coff[4], kiters[4], act[4], araw[4], rsmode[4];
};

#define PADK 136

__global__ __launch_bounds__(256, 2) void gemmL(GD4 g, const u32* __restrict__ flag) {
    __shared__ __align__(16) u16 As[16][PADK];
    __shared__ __align__(16) u16 Bs[128][PADK];
    int z = blockIdx.y;
    bool af32 = g.araw[z] && (flag[0] != 0);
    const void* A = g.A[z];
    const u16* BT = g.BT[z];
    int lda = g.lda[z], ldb = g.ldb[z];
    int kiters = g.kiters[z];
    int tid = threadIdx.x;
    int lane = tid & 63, wv = tid >> 6;
    int mrow = lane & 15, quad = lane >> 4;
    int m0 = blockIdx.x * 16;
    int c0 = wv * 32;
    int sr = tid >> 4, sk = (tid & 15) * 8;
    f32x4 acc0 = {0.f, 0.f, 0.f, 0.f}, acc1 = {0.f, 0.f, 0.f, 0.f};

    short8 ra, rb[8];
    auto ldstage = [&](int kb) {
        if (af32) {
            const float* A32 = (const float*)A;
            const float4* p = (const float4*)(A32 + (size_t)(m0 + sr) * lda + kb + sk);
            float4 f0 = p[0], f1 = p[1];
            ra = packbf8(f0, f1);
        } else {
            ra = *(const short8*)((const u16*)A + (size_t)(m0 + sr) * lda + kb + sk);
        }
        const u16* bbase = BT + (size_t)sr * ldb + kb + sk;
        #pragma unroll
        for (int i = 0; i < 8; i++)
            rb[i] = *(const short8*)(bbase + (size_t)i * 16 * ldb);
    };
    auto ststage = [&]() {
        *(short8*)(&As[sr][sk]) = ra;
        #pragma unroll
        for (int i = 0; i < 8; i++)
            *(short8*)(&Bs[i * 16 + sr][sk]) = rb[i];
    };
    auto compute = [&]() {
        #pragma unroll
        for (int ks = 0; ks < 4; ks++) {
            short8 af = *(const short8*)(&As[mrow][ks * 32 + quad * 8]);
            short8 b0 = *(const short8*)(&Bs[c0 + mrow][ks * 32 + quad * 8]);
            short8 b1 = *(const short8*)(&Bs[c0 + 16 + mrow][ks * 32 + quad * 8]);
            acc0 = __builtin_amdgcn_mfma_f32_16x16x32_bf16(af, b0, acc0, 0, 0, 0);
            acc1 = __builtin_amdgcn_mfma_f32_16x16x32_bf16(af, b1, acc1, 0, 0, 0);
        }
    };

    ldstage(0);
    #pragma unroll 1
    for (int it = 0; it < kiters - 1; ++it) {
        ststage();
        __syncthreads();
        ldstage((it + 1) * 128);
        compute();
        __syncthreads();
    }
    ststage();
    __syncthreads();
    compute();

    const float* rs = g.rs[z];
    int rsmode = g.rsmode[z];
    const u16* bi = g.bias[z];
    u16* C = g.C[z];
    int ldc = g.ldc[z], coff = g.coff[z], act = g.act[z];
    int n0 = c0 + mrow, n1 = n0 + 16;
    float bv0 = bi ? bf2f(bi[n0]) : 0.f;
    float bv1 = bi ? bf2f(bi[n1]) : 0.f;
    #pragma unroll
    for (int r = 0; r < 4; r++) {
        int row = m0 + quad * 4 + r;
        float v0 = acc0[r], v1 = acc1[r];
        if (rsmode == 1) { float sc = rs[row]; v0 *= sc; v1 *= sc; }
        v0 += bv0; v1 += bv1;
        if (act) { v0 = seluf(v0); v1 = seluf(v1); }
        C[(size_t)row * ldc + coff + n0] = f2bf(v0);
        C[(size_t)row * ldc + coff + n1] = f2bf(v1);
    }
}

// ---------------- pair gather ----------
__global__ __launch_bounds__(256) void xbuild(
    const u16* __restrict__ he, const u16* __restrict__ hp,
    const int* __restrict__ di, const int* __restrict__ dr, u16* __restrict__ X) {
    int idx = blockIdx.x * 256 + threadIdx.x;  // < B*64
    int d2 = idx & 63;
    int b = idx >> 6;
    int ia = di[b], ic = dr[b];
    u32 ue = ((const u32*)he)[ia * 64 + d2];
    u32 up = ((const u32*)hp)[ic * 64 + d2];
    float lo = bf2f((u16)(ue & 0xffff)) * bf2f((u16)(up & 0xffff));
    float hi = bf2f((u16)(ue >> 16)) * bf2f((u16)(up >> 16));
    ((u32*)X)[idx] = (u32)f2bf(lo) | ((u32)f2bf(hi) << 16);
}

// ---------------- z, sigmoid, loss (FLOAT32 out: out[0]=loss, out[1+b]=sig) --
__global__ __launch_bounds__(256) void zloss(
    const u16* __restrict__ X2, const u16* __restrict__ wpred,
    const u16* __restrict__ bpred, const int* __restrict__ labels,
    float* __restrict__ out, float* __restrict__ part) {
    __shared__ float wp[128];
    __shared__ float ls[256];
    int tid = threadIdx.x;
    if (tid < 128) wp[tid] = bf2f(wpred[tid]);
    __syncthreads();
    int b = blockIdx.x * 256 + tid;
    const uint4* xp = (const uint4*)(X2 + (size_t)b * 128);
    float z = 0.f;
    #pragma unroll
    for (int i = 0; i < 16; i++) {
        uint4 q = xp[i];
        u32 u[4] = {q.x, q.y, q.z, q.w};
        #pragma unroll
        for (int c = 0; c < 4; c++) {
            z += bf2f((u16)(u[c] & 0xffff)) * wp[i * 8 + c * 2];
            z += bf2f((u16)(u[c] >> 16)) * wp[i * 8 + c * 2 + 1];
        }
    }
    z += bf2f(bpred[0]);
    out[1 + b] = 1.f / (1.f + __expf(-z));
    float y = (float)labels[b];
    ls[tid] = fmaxf(z, 0.f) - z * y + log1pf(__expf(-fabsf(z)));
    __syncthreads();
    for (int o = 128; o > 0; o >>= 1) {
        if (tid < o) ls[tid] += ls[tid + o];
        __syncthreads();
    }
    if (tid == 0) part[blockIdx.x] = ls[0];
}

__global__ void finloss(const float* __restrict__ part, float* __restrict__ out) {
    __shared__ float s[64];
    s[threadIdx.x] = part[threadIdx.x];
    __syncthreads();
    for (int o = 32; o > 0; o >>= 1) {
        if (threadIdx.x < o) s[threadIdx.x] += s[threadIdx.x + o];
        __syncthreads();
    }
    if (threadIdx.x == 0) out[0] = s[0] * (1.f / 16384.f);
}

// ---------------- launch ----------------
extern "C" void kernel_launch(void* const* d_in, const int* in_sizes, int n_in,
                              void* d_out, int out_size, void* d_ws, size_t ws_size,
                              hipStream_t stream) {
    const void* e_p_adj = d_in[0];
    const void* e_e_adj = d_in[1];
    const void* p_p_adj = d_in[2];
    const int* in_dis  = (const int*)d_in[3];
    const int* in_drug = (const int*)d_in[4];
    const int* labels  = (const int*)d_in[5];
    float* out = (float*)d_out;

    // -------- workspace layout (~19.6 MB; dual fired in r13 => ws >= 23.6 MB)
    char* ws = (char*)d_ws;
    size_t off = 0;
    auto take = [&](size_t bytes) { char* p = ws + off; off = (off + bytes + 255) & ~(size_t)255; return p; };
    u16*   Xbuf  = (u16*)take((size_t)2 * BB * 128 * 2);  // X (4MB) + X1 (4MB)
    u16*   epT   = (u16*)take((size_t)2048 * 2048 * 2);   // 8 MB; X2 aliases after sagg
    float* ko_d  = (float*)take((size_t)2048 * 32 * 4);
    float* qs_d  = (float*)take((size_t)2048 * 32 * 4);
    float* ko_p  = (float*)take((size_t)2048 * 32 * 4);
    float* qs_p  = (float*)take((size_t)2048 * 32 * 4);
    u16*   A_e   = (u16*)take((size_t)2048 * 256 * 2);
    u16*   A_p   = (u16*)take((size_t)2048 * 256 * 2);
    u16*   WcTe  = (u16*)take((size_t)128 * 256 * 2);
    u16*   WcTp  = (u16*)take((size_t)128 * 256 * 2);
    u16*   W1T   = (u16*)take((size_t)128 * 128 * 2);
    u16*   W2T   = (u16*)take((size_t)128 * 128 * 2);
    u16*   b_e   = (u16*)take(256);
    u16*   b_p   = (u16*)take(256);
    u16*   h_e   = (u16*)take((size_t)2048 * 128 * 2);
    u16*   h_p   = (u16*)take((size_t)2048 * 128 * 2);
    float* esum_d = (float*)take(128 * 4);
    float* esum_p = (float*)take(128 * 4);
    float* part  = (float*)take(64 * 4);
    u16*   canon = (u16*)take((size_t)700000 * 2);
    u32*   flag  = (u32*)take(256);
    u16* X  = Xbuf;
    u16* X1 = Xbuf + (size_t)BB * 128;
    u16* X2 = epT;   // epT dead after sagg

    // -------- canonical parameter table --------
    const int segidx[NSEG] = {6, 7, 14, 18, 8, 22, 11, 24, 26, 28,
                              15, 16, 17, 19, 20, 21,
                              9, 10, 12, 13, 23, 25, 27, 29, 30, 31};
    const int segn[NSEG]   = {262144, 262144, 8192, 8192, 16384, 16384, 16384, 16384, 16384, 16384,
                              32, 32, 1, 32, 32, 1,
                              128, 128, 128, 128, 128, 128, 128, 128, 128, 1};
    CvtArgs ca;
    u16* cp[NSEG];
    {
        int o = 0;
        for (int i = 0; i < NSEG; i++) {
            ca.src[i] = d_in[segidx[i]];
            ca.off[i] = o;
            ca.n[i] = segn[i];
            cp[i] = canon + o;
            o += (segn[i] + 15) & ~15;
        }
    }
    u16 *cdemb = cp[0], *cpemb = cp[1], *cWa1d = cp[2], *cWa1p = cp[3];
    u16 *cWdg = cp[4], *cWd2 = cp[5], *cWpg = cp[6], *cWp3 = cp[7];
    u16 *cW1 = cp[8], *cW2 = cp[9];
    u16 *cba1d = cp[10], *cWa2d = cp[11], *cba2d = cp[12];
    u16 *cba1p = cp[13], *cWa2p = cp[14], *cba2p = cp[15];
    u16 *cbdg_lin = cp[16], *cbdg = cp[17], *cbpg_lin = cp[18], *cbpg = cp[19];
    u16 *cbd2 = cp[20], *cbp3 = cp[21], *cmb1 = cp[22], *cmb2 = cp[23];
    u16 *cWpred = cp[24], *cbpred = cp[25];

    // -------- 0. dtype detection + canonicalization --------
    detectk<<<1, 256, 0, stream>>>(d_in[6], flag);
    cvtk<<<dim3(64, NSEG), 256, 0, stream>>>(ca, canon, flag);

    // -------- 1. prep --------
    tpose_smalls<<<dim3(4, 4, 6), dim3(32, 8), 0, stream>>>(
        cW1, cW2, cWdg, cWd2, cWpg, cWp3, W1T, W2T, WcTe, WcTp);
    biasc<<<1, 128, 0, stream>>>(cbdg_lin, cbdg, cbd2, b_e, cbpg_lin, cbpg, cbp3, b_p);
    tposeEP<<<dim3(64, 64), dim3(32, 8), 0, stream>>>(e_p_adj, epT, flag);
    embsumk<<<2, 1024, 0, stream>>>(cdemb, cpemb, esum_d, esum_p);
    koqs<<<dim3(2048, 4), 128, 0, stream>>>(cdemb, cpemb, cWa1d, cba1d, cWa1p, cba1p,
                                            ko_d, qs_d, ko_p, qs_p);

    // -------- 2. sparse fused attention + knn aggregation (one launch) ------
    {
        SG s;
        // z=0: disease attention over drugs
        s.adj[0] = e_p_adj; s.adjbf[0] = 0; s.qs[0] = qs_d; s.ko[0] = ko_d;
        s.w2[0] = cWa2d; s.b2[0] = cba2d; s.embsum[0] = esum_p; s.emb[0] = cpemb;
        s.outp[0] = A_e; s.coff[0] = 0; s.mode[0] = 0;
        // z=1: disease knn (e_e)
        s.adj[1] = e_e_adj; s.adjbf[1] = 0; s.qs[1] = nullptr; s.ko[1] = nullptr;
        s.w2[1] = nullptr; s.b2[1] = nullptr; s.embsum[1] = nullptr; s.emb[1] = cdemb;
        s.outp[1] = A_e; s.coff[1] = 128; s.mode[1] = 1;
        // z=2: drug attention over diseases (transposed adjacency)
        s.adj[2] = epT; s.adjbf[2] = 1; s.qs[2] = qs_p; s.ko[2] = ko_p;
        s.w2[2] = cWa2p; s.b2[2] = cba2p; s.embsum[2] = esum_d; s.emb[2] = cdemb;
        s.outp[2] = A_p; s.coff[2] = 0; s.mode[2] = 0;
        // z=3: drug knn (p_p)
        s.adj[3] = p_p_adj; s.adjbf[3] = 0; s.qs[3] = nullptr; s.ko[3] = nullptr;
        s.w2[3] = nullptr; s.b2[3] = nullptr; s.embsum[3] = nullptr; s.emb[3] = cpemb;
        s.outp[3] = A_p; s.coff[3] = 128; s.mode[3] = 1;
        sagg<<<dim3(2048, 4), 256, 0, stream>>>(s, flag);
    }

    auto setd = [](GD4& g, int z, const void* A, int lda, const u16* BT, int ldb,
                   u16* C, int ldc, int coff, int ki, const u16* bi,
                   const float* rs, int act, int araw, int rm) {
        g.A[z] = A; g.lda[z] = lda; g.BT[z] = BT; g.ldb[z] = ldb;
        g.C[z] = C; g.ldc[z] = ldc; g.coff[z] = coff; g.kiters[z] = ki;
        g.bias[z] = bi; g.rs[z] = rs; g.act[z] = act; g.araw[z] = araw; g.rsmode[z] = rm;
    };

    // -------- 3. combine GEMMs (bias + SELU), batched ----------------------
    {
        GD4 g;
        setd(g, 0, A_e, 256, WcTe, 256, h_e, 128, 0, 2, b_e, nullptr, 1, 0, 0);
        setd(g, 1, A_p, 256, WcTp, 256, h_p, 128, 0, 2, b_p, nullptr, 1, 0, 0);
        setd(g, 2, A_e, 256, WcTe, 256, h_e, 128, 0, 2, b_e, nullptr, 1, 0, 0);
        setd(g, 3, A_e, 256, WcTe, 256, h_e, 128, 0, 2, b_e, nullptr, 1, 0, 0);
        gemmL<<<dim3(128, 2), 256, 0, stream>>>(g, flag);
    }

    // -------- 4. pair MLP --------
    xbuild<<<4096, 256, 0, stream>>>(h_e, h_p, in_dis, in_drug, X);
    {
        GD4 g;
        setd(g, 0, X, 128, W1T, 128, X1, 128, 0, 1, cmb1, nullptr, 1, 0, 0);
        setd(g, 1, X, 128, W1T, 128, X1, 128, 0, 1, cmb1, nullptr, 1, 0, 0);
        setd(g, 2, X, 128, W1T, 128, X1, 128, 0, 1, cmb1, nullptr, 1, 0, 0);
        setd(g, 3, X, 128, W1T, 128, X1, 128, 0, 1, cmb1, nullptr, 1, 0, 0);
        gemmL<<<dim3(1024, 1), 256, 0, stream>>>(g, flag);
    }
    {
        GD4 g;
        setd(g, 0, X1, 128, W2T, 128, X2, 128, 0, 1, cmb2, nullptr, 1, 0, 0);
        setd(g, 1, X1, 128, W2T, 128, X2, 128, 0, 1, cmb2, nullptr, 1, 0, 0);
        setd(g, 2, X1, 128, W2T, 128, X2, 128, 0, 1, cmb2, nullptr, 1, 0, 0);
        setd(g, 3, X1, 128, W2T, 128, X2, 128, 0, 1, cmb2, nullptr, 1, 0, 0);
        gemmL<<<dim3(1024, 1), 256, 0, stream>>>(g, flag);
    }

    // -------- 5. z / sigmoid / loss --------
    zloss<<<64, 256, 0, stream>>>(X2, cWpred, cbpred, labels, out, part);
    finloss<<<1, 64, 0, stream>>>(part, out);
}

// Round 15
// 369.029 us; speedup vs baseline: 1.1234x; 1.1234x over previous
//
#include <hip/hip_runtime.h>

#define ND   2048
#define BB   16384

typedef unsigned short u16;
typedef unsigned int u32;
typedef unsigned long long u64;
typedef __attribute__((ext_vector_type(8))) short short8;
typedef __attribute__((ext_vector_type(4))) float f32x4;

__device__ inline float bf2f(u16 u) {
    union { u32 i; float f; } v; v.i = ((u32)u) << 16; return v.f;
}
__device__ inline u16 f2bf(float f) {
    union { float f; u32 i; } v; v.f = f;
    u32 i = v.i + 0x7fffu + ((v.i >> 16) & 1u);
    return (u16)(i >> 16);
}
__device__ inline float seluf(float x) {
    const float sc = 1.0507009873554805f, al = 1.6732632423543772f;
    return x > 0.f ? sc * x : sc * al * expm1f(x);
}
__device__ inline short8 packbf8(float4 f0, float4 f1) {
    short8 a;
    a[0] = (short)f2bf(f0.x); a[1] = (short)f2bf(f0.y);
    a[2] = (short)f2bf(f0.z); a[3] = (short)f2bf(f0.w);
    a[4] = (short)f2bf(f1.x); a[5] = (short)f2bf(f1.y);
    a[6] = (short)f2bf(f1.z); a[7] = (short)f2bf(f1.w);
    return a;
}

// ---------------- dtype sniffer ----------------
__global__ void detectk(const void* __restrict__ demb, u32* __restrict__ flag) {
    const u16* p = (const u16*)demb;
    int tid = threadIdx.x;  // 256
    int sane = 0;
    #pragma unroll
    for (int i = 0; i < 2; i++) {
        u16 u = p[4 * tid + 2 * i];
        int e = (u >> 7) & 0xFF;
        if (u == 0 || (e >= 0x66 && e <= 0x8C)) sane++;
    }
    __shared__ int red[256];
    red[tid] = sane; __syncthreads();
    for (int o = 128; o > 0; o >>= 1) {
        if (tid < o) red[tid] += red[tid + o];
        __syncthreads();
    }
    if (tid == 0) flag[0] = (red[0] < 300) ? 1u : 0u;
}

// ---------------- canonical bf16 conversion (26 segments, one launch) -------
#define NSEG 26
struct CvtArgs { const void* src[NSEG]; int off[NSEG]; int n[NSEG]; };

__global__ __launch_bounds__(256) void cvtk(CvtArgs a, u16* __restrict__ base,
                                            const u32* __restrict__ flag) {
    int seg = blockIdx.y;
    int n = a.n[seg];
    const void* s = a.src[seg];
    u16* d = base + a.off[seg];
    bool f32 = flag[0] != 0;
    int stride = gridDim.x * blockDim.x;
    for (int i = blockIdx.x * blockDim.x + threadIdx.x; i < n; i += stride)
        d[i] = f32 ? f2bf(((const float*)s)[i]) : ((const u16*)s)[i];
}

// ---------------- small 128x128 transposes ----------------
__device__ inline void tpose_body(const u16* in, int R, int C,
                                  u16* out, int ldo, int ooff,
                                  u16 (*tile)[33]) {
    int c0 = blockIdx.x * 32, r0 = blockIdx.y * 32;
    int x = c0 + threadIdx.x;
    for (int i = threadIdx.y; i < 32; i += 8) {
        int r = r0 + i;
        tile[i][threadIdx.x] = (r < R && x < C) ? in[(size_t)r * C + x] : (u16)0;
    }
    __syncthreads();
    int rr = r0 + threadIdx.x;
    for (int i = threadIdx.y; i < 32; i += 8) {
        int cc = c0 + i;
        if (cc < C && rr < R) out[(size_t)cc * ldo + ooff + rr] = tile[threadIdx.x][i];
    }
}

__global__ void tpose_smalls(const u16* s0, const u16* s1, const u16* s2,
                             const u16* s3, const u16* s4, const u16* s5,
                             u16* W1T, u16* W2T, u16* WcTe, u16* WcTp) {
    __shared__ u16 tile[32][33];
    const u16* in; u16* out; int ldo, ooff;
    switch (blockIdx.z) {
        case 0:  in = s0; out = W1T;  ldo = 128; ooff = 0;   break;
        case 1:  in = s1; out = W2T;  ldo = 128; ooff = 0;   break;
        case 2:  in = s2; out = WcTe; ldo = 256; ooff = 0;   break;
        case 3:  in = s3; out = WcTe; ldo = 256; ooff = 128; break;
        case 4:  in = s4; out = WcTp; ldo = 256; ooff = 0;   break;
        default: in = s5; out = WcTp; ldo = 256; ooff = 128; break;
    }
    tpose_body(in, 128, 128, out, ldo, ooff, tile);
}

// ---------------- e_p adjacency transpose -> bf16 ----------------
__global__ void tposeEP(const void* __restrict__ in, u16* __restrict__ out,
                        const u32* __restrict__ flag) {
    __shared__ u16 tile[32][33];
    bool f32 = flag[0] != 0;
    int c0 = blockIdx.x * 32, r0 = blockIdx.y * 32;
    int x = c0 + threadIdx.x;
    for (int i = threadIdx.y; i < 32; i += 8) {
        int r = r0 + i;
        tile[i][threadIdx.x] = f32 ? f2bf(((const float*)in)[(size_t)r * 2048 + x])
                                   : ((const u16*)in)[(size_t)r * 2048 + x];
    }
    __syncthreads();
    int rr = r0 + threadIdx.x;
    for (int i = threadIdx.y; i < 32; i += 8)
        out[(size_t)(c0 + i) * 2048 + rr] = tile[threadIdx.x][i];
}

// ---------------- combined biases ----------------
__global__ void biasc(const u16* a0, const u16* a1, const u16* a2, u16* o0,
                      const u16* b0, const u16* b1, const u16* b2, u16* o1) {
    int t = threadIdx.x;  // 128
    o0[t] = f2bf(bf2f(a0[t]) + bf2f(a1[t]) + bf2f(a2[t]));
    o1[t] = f2bf(bf2f(b0[t]) + bf2f(b1[t]) + bf2f(b2[t]));
}

// ---------------- embedding column sums (f32) ----------------
__global__ __launch_bounds__(1024) void embsumk(const u16* __restrict__ demb,
                                                const u16* __restrict__ pemb,
                                                float* __restrict__ se,
                                                float* __restrict__ sp) {
    const u16* src = blockIdx.x ? pemb : demb;
    float* dst = blockIdx.x ? sp : se;
    int d = threadIdx.x & 127, r8 = threadIdx.x >> 7;
    float s = 0.f;
    for (int r = r8; r < 2048; r += 8)
        s += bf2f(src[(size_t)r * 128 + d]);
    __shared__ float part[8][128];
    part[r8][d] = s;
    __syncthreads();
    if (threadIdx.x < 128) {
        float t = 0.f;
        #pragma unroll
        for (int i = 0; i < 8; i++) t += part[i][threadIdx.x];
        dst[threadIdx.x] = t;
    }
}

// ---------------- ko / qs projections ----------
__global__ __launch_bounds__(128) void koqs(
    const u16* __restrict__ demb, const u16* __restrict__ pemb,
    const u16* __restrict__ Wa1d, const u16* __restrict__ ba1d,
    const u16* __restrict__ Wa1p, const u16* __restrict__ ba1p,
    float* __restrict__ ko_d, float* __restrict__ qs_d,
    float* __restrict__ ko_p, float* __restrict__ qs_p) {
    int row = blockIdx.x, m = blockIdx.y, tid = threadIdx.x;
    const u16* src; const u16* W; const u16* bias; float* out;
    switch (m) {
        case 0:  src = pemb; W = Wa1d;            bias = nullptr; out = ko_d; break;
        case 1:  src = demb; W = Wa1d + 128 * 32; bias = ba1d;    out = qs_d; break;
        case 2:  src = demb; W = Wa1p;            bias = nullptr; out = ko_p; break;
        default: src = pemb; W = Wa1p + 128 * 32; bias = ba1p;    out = qs_p; break;
    }
    __shared__ float x[128];
    __shared__ float red[128];
    x[tid] = bf2f(src[(size_t)row * 128 + tid]);
    __syncthreads();
    int a = tid & 31, part = tid >> 5;
    float s = 0.f;
    #pragma unroll
    for (int k = 0; k < 32; k++) s += x[part * 32 + k] * bf2f(W[(part * 32 + k) * 32 + a]);
    red[tid] = s;
    __syncthreads();
    if (part == 0) {
        float t = red[a] + red[a + 32] + red[a + 64] + red[a + 96];
        if (bias) t += bf2f(bias[a]);
        out[(size_t)row * 32 + a] = t;
    }
}

// ---------------- sparse fused attention/knn aggregation v2 ----------------
// exp(s*adj) = 1 + adj*expm1(s)  (adj in {0,1}, s>=0)
// 512 threads, ballot compaction (no per-edge atomics), preloaded scan,
// 4-way edge-parallel accumulation with manual 4-deep unroll.
#define ECAP 512
struct SG {
    const void* adj[4];
    int adjbf[4];            // 1 = adjacency always bf16 (epT); 0 = flag decides
    const float* qs[4]; const float* ko[4];
    const u16* w2[4]; const u16* b2[4];
    const float* embsum[4];
    const u16* emb[4];
    u16* outp[4]; int coff[4];
    int mode[4];             // 0 attention, 1 knn
};

__global__ __launch_bounds__(512, 4) void sagg2(SG p, const u32* __restrict__ flag) {
    __shared__ float accQ[4][128];
    __shared__ float qsh[32], w2sh[32];
    __shared__ float wlist[ECAP];
    __shared__ int jlist[ECAP];
    __shared__ float red[512];
    __shared__ int ecnt;
    __shared__ float wsum_sh;
    int z = blockIdx.y;
    int row = blockIdx.x;
    int tid = threadIdx.x;
    int lane = tid & 63;
    int mode = p.mode[z];
    bool f32a = (p.adjbf[z] == 0) && (flag[0] != 0);
    const float* adjf = (const float*)p.adj[z];
    const u16*   adjh = (const u16*)p.adj[z];
    if (tid < 128) { accQ[0][tid] = 0.f; accQ[1][tid] = 0.f;
                     accQ[2][tid] = 0.f; accQ[3][tid] = 0.f; }
    if (tid == 0) ecnt = 0;
    if (mode == 0) {
        if (tid < 32) qsh[tid] = p.qs[z][(size_t)row * 32 + tid];
        else if (tid < 64) w2sh[tid - 32] = bf2f(p.w2[z][tid - 32]);
    }
    __syncthreads();
    float b2v = (mode == 0) ? bf2f(p.b2[z][0]) : 0.f;
    const float* ko = p.ko[z];

    // preload all 4 scan chunks (independent loads in flight)
    float av[4];
    #pragma unroll
    for (int c = 0; c < 4; c++) {
        int j = c * 512 + tid;
        av[c] = f32a ? adjf[(size_t)row * 2048 + j]
                     : bf2f(adjh[(size_t)row * 2048 + j]);
    }
    u64 ltmask = ((u64)1 << lane) - 1;
    #pragma unroll
    for (int c = 0; c < 4; c++) {
        int j = c * 512 + tid;
        bool has = av[c] != 0.f;
        float w = 0.f;
        if (has) {
            if (mode == 0) {
                const float4* kp = (const float4*)(ko + (size_t)j * 32);
                float s = 0.f;
                #pragma unroll
                for (int qd = 0; qd < 8; qd++) {
                    float4 kv = kp[qd];
                    s += fmaxf(qsh[qd * 4 + 0] + kv.x, 0.f) * w2sh[qd * 4 + 0];
                    s += fmaxf(qsh[qd * 4 + 1] + kv.y, 0.f) * w2sh[qd * 4 + 1];
                    s += fmaxf(qsh[qd * 4 + 2] + kv.z, 0.f) * w2sh[qd * 4 + 2];
                    s += fmaxf(qsh[qd * 4 + 3] + kv.w, 0.f) * w2sh[qd * 4 + 3];
                }
                s = fmaxf(s + b2v, 0.f);
                w = expm1f(s);
            } else {
                w = av[c];
            }
        }
        u64 mask = __ballot(has);
        int cnt = __popcll(mask);
        int base0 = 0;
        if (lane == 0 && cnt) base0 = atomicAdd(&ecnt, cnt);
        int base = __shfl(base0, 0, 64);
        int pos = base + (int)__popcll(mask & ltmask);
        if (has && pos < ECAP) { jlist[pos] = j; wlist[pos] = w; }
    }
    __syncthreads();
    int E = min(ecnt, ECAP);
    // weight-sum reduction (512 threads over E<=512)
    red[tid] = (tid < E) ? wlist[tid] : 0.f;
    __syncthreads();
    for (int o = 256; o > 0; o >>= 1) {
        if (tid < o) red[tid] += red[tid + o];
        __syncthreads();
    }
    if (tid == 0) wsum_sh = red[0];
    // edge accumulation: 4-way edge parallel, 4-deep unroll (16 in flight)
    int d = tid & 127, q = tid >> 7;
    const u16* emb = p.emb[z];
    float acc = 0.f;
    int e = q;
    for (; e + 12 < E; e += 16) {
        float w0 = wlist[e],      w1 = wlist[e + 4];
        float w2 = wlist[e + 8],  w3 = wlist[e + 12];
        int j0 = jlist[e],        j1 = jlist[e + 4];
        int j2 = jlist[e + 8],    j3 = jlist[e + 12];
        float v0 = bf2f(emb[(size_t)j0 * 128 + d]);
        float v1 = bf2f(emb[(size_t)j1 * 128 + d]);
        float v2 = bf2f(emb[(size_t)j2 * 128 + d]);
        float v3 = bf2f(emb[(size_t)j3 * 128 + d]);
        acc += w0 * v0 + w1 * v1 + w2 * v2 + w3 * v3;
    }
    for (; e < E; e += 4)
        acc += wlist[e] * bf2f(emb[(size_t)jlist[e] * 128 + d]);
    accQ[q][d] = acc;
    __syncthreads();
    if (tid < 128) {
        float v = accQ[0][tid] + accQ[1][tid] + accQ[2][tid] + accQ[3][tid];
        float denom;
        if (mode == 0) { v += p.embsum[z][tid]; denom = 2048.f + wsum_sh; }
        else denom = wsum_sh + 1e-8f;
        p.outp[z][(size_t)row * 256 + p.coff[z] + tid] = f2bf(v / denom);
    }
}

// ---------------- MFMA GEMM: canonical LDS-tiled (guide §5) -----------------
struct GD4 {
    const void* A[4]; const u16* BT[4]; u16* C[4];
    const u16* bias[4]; const float* rs[4];
    int lda[4], ldb[4], ldc[4], coff[4], kiters[4], act[4], araw[4], rsmode[4];
};

#define PADK 136

__global__ __launch_bounds__(256, 2) void gemmL(GD4 g, const u32* __restrict__ flag) {
    __shared__ __align__(16) u16 As[16][PADK];
    __shared__ __align__(16) u16 Bs[128][PADK];
    int z = blockIdx.y;
    bool af32 = g.araw[z] && (flag[0] != 0);
    const void* A = g.A[z];
    const u16* BT = g.BT[z];
    int lda = g.lda[z], ldb = g.ldb[z];
    int kiters = g.kiters[z];
    int tid = threadIdx.x;
    int lane = tid & 63, wv = tid >> 6;
    int mrow = lane & 15, quad = lane >> 4;
    int m0 = blockIdx.x * 16;
    int c0 = wv * 32;
    int sr = tid >> 4, sk = (tid & 15) * 8;
    f32x4 acc0 = {0.f, 0.f, 0.f, 0.f}, acc1 = {0.f, 0.f, 0.f, 0.f};

    short8 ra, rb[8];
    auto ldstage = [&](int kb) {
        if (af32) {
            const float* A32 = (const float*)A;
            const float4* p = (const float4*)(A32 + (size_t)(m0 + sr) * lda + kb + sk);
            float4 f0 = p[0], f1 = p[1];
            ra = packbf8(f0, f1);
        } else {
            ra = *(const short8*)((const u16*)A + (size_t)(m0 + sr) * lda + kb + sk);
        }
        const u16* bbase = BT + (size_t)sr * ldb + kb + sk;
        #pragma unroll
        for (int i = 0; i < 8; i++)
            rb[i] = *(const short8*)(bbase + (size_t)i * 16 * ldb);
    };
    auto ststage = [&]() {
        *(short8*)(&As[sr][sk]) = ra;
        #pragma unroll
        for (int i = 0; i < 8; i++)
            *(short8*)(&Bs[i * 16 + sr][sk]) = rb[i];
    };
    auto compute = [&]() {
        #pragma unroll
        for (int ks = 0; ks < 4; ks++) {
            short8 af = *(const short8*)(&As[mrow][ks * 32 + quad * 8]);
            short8 b0 = *(const short8*)(&Bs[c0 + mrow][ks * 32 + quad * 8]);
            short8 b1 = *(const short8*)(&Bs[c0 + 16 + mrow][ks * 32 + quad * 8]);
            acc0 = __builtin_amdgcn_mfma_f32_16x16x32_bf16(af, b0, acc0, 0, 0, 0);
            acc1 = __builtin_amdgcn_mfma_f32_16x16x32_bf16(af, b1, acc1, 0, 0, 0);
        }
    };

    ldstage(0);
    #pragma unroll 1
    for (int it = 0; it < kiters - 1; ++it) {
        ststage();
        __syncthreads();
        ldstage((it + 1) * 128);
        compute();
        __syncthreads();
    }
    ststage();
    __syncthreads();
    compute();

    const float* rs = g.rs[z];
    int rsmode = g.rsmode[z];
    const u16* bi = g.bias[z];
    u16* C = g.C[z];
    int ldc = g.ldc[z], coff = g.coff[z], act = g.act[z];
    int n0 = c0 + mrow, n1 = n0 + 16;
    float bv0 = bi ? bf2f(bi[n0]) : 0.f;
    float bv1 = bi ? bf2f(bi[n1]) : 0.f;
    #pragma unroll
    for (int r = 0; r < 4; r++) {
        int row = m0 + quad * 4 + r;
        float v0 = acc0[r], v1 = acc1[r];
        if (rsmode == 1) { float sc = rs[row]; v0 *= sc; v1 *= sc; }
        v0 += bv0; v1 += bv1;
        if (act) { v0 = seluf(v0); v1 = seluf(v1); }
        C[(size_t)row * ldc + coff + n0] = f2bf(v0);
        C[(size_t)row * ldc + coff + n1] = f2bf(v1);
    }
}

// ---------------- pair gather ----------
__global__ __launch_bounds__(256) void xbuild(
    const u16* __restrict__ he, const u16* __restrict__ hp,
    const int* __restrict__ di, const int* __restrict__ dr, u16* __restrict__ X) {
    int idx = blockIdx.x * 256 + threadIdx.x;  // < B*64
    int d2 = idx & 63;
    int b = idx >> 6;
    int ia = di[b], ic = dr[b];
    u32 ue = ((const u32*)he)[ia * 64 + d2];
    u32 up = ((const u32*)hp)[ic * 64 + d2];
    float lo = bf2f((u16)(ue & 0xffff)) * bf2f((u16)(up & 0xffff));
    float hi = bf2f((u16)(ue >> 16)) * bf2f((u16)(up >> 16));
    ((u32*)X)[idx] = (u32)f2bf(lo) | ((u32)f2bf(hi) << 16);
}

// ---------------- z, sigmoid, loss (FLOAT32 out: out[0]=loss, out[1+b]=sig) --
__global__ __launch_bounds__(256) void zloss(
    const u16* __restrict__ X2, const u16* __restrict__ wpred,
    const u16* __restrict__ bpred, const int* __restrict__ labels,
    float* __restrict__ out, float* __restrict__ part) {
    __shared__ float wp[128];
    __shared__ float ls[256];
    int tid = threadIdx.x;
    if (tid < 128) wp[tid] = bf2f(wpred[tid]);
    __syncthreads();
    int b = blockIdx.x * 256 + tid;
    const uint4* xp = (const uint4*)(X2 + (size_t)b * 128);
    float z = 0.f;
    #pragma unroll
    for (int i = 0; i < 16; i++) {
        uint4 q = xp[i];
        u32 u[4] = {q.x, q.y, q.z, q.w};
        #pragma unroll
        for (int c = 0; c < 4; c++) {
            z += bf2f((u16)(u[c] & 0xffff)) * wp[i * 8 + c * 2];
            z += bf2f((u16)(u[c] >> 16)) * wp[i * 8 + c * 2 + 1];
        }
    }
    z += bf2f(bpred[0]);
    out[1 + b] = 1.f / (1.f + __expf(-z));
    float y = (float)labels[b];
    ls[tid] = fmaxf(z, 0.f) - z * y + log1pf(__expf(-fabsf(z)));
    __syncthreads();
    for (int o = 128; o > 0; o >>= 1) {
        if (tid < o) ls[tid] += ls[tid + o];
        __syncthreads();
    }
    if (tid == 0) part[blockIdx.x] = ls[0];
}

__global__ void finloss(const float* __restrict__ part, float* __restrict__ out) {
    __shared__ float s[64];
    s[threadIdx.x] = part[threadIdx.x];
    __syncthreads();
    for (int o = 32; o > 0; o >>= 1) {
        if (threadIdx.x < o) s[threadIdx.x] += s[threadIdx.x + o];
        __syncthreads();
    }
    if (threadIdx.x == 0) out[0] = s[0] * (1.f / 16384.f);
}

// ---------------- launch ----------------
extern "C" void kernel_launch(void* const* d_in, const int* in_sizes, int n_in,
                              void* d_out, int out_size, void* d_ws, size_t ws_size,
                              hipStream_t stream) {
    const void* e_p_adj = d_in[0];
    const void* e_e_adj = d_in[1];
    const void* p_p_adj = d_in[2];
    const int* in_dis  = (const int*)d_in[3];
    const int* in_drug = (const int*)d_in[4];
    const int* labels  = (const int*)d_in[5];
    float* out = (float*)d_out;

    // -------- workspace layout (~19.6 MB) --------
    char* ws = (char*)d_ws;
    size_t off = 0;
    auto take = [&](size_t bytes) { char* p = ws + off; off = (off + bytes + 255) & ~(size_t)255; return p; };
    u16*   Xbuf  = (u16*)take((size_t)2 * BB * 128 * 2);  // X (4MB) + X1 (4MB)
    u16*   epT   = (u16*)take((size_t)2048 * 2048 * 2);   // 8 MB; X2 aliases after sagg
    float* ko_d  = (float*)take((size_t)2048 * 32 * 4);
    float* qs_d  = (float*)take((size_t)2048 * 32 * 4);
    float* ko_p  = (float*)take((size_t)2048 * 32 * 4);
    float* qs_p  = (float*)take((size_t)2048 * 32 * 4);
    u16*   A_e   = (u16*)take((size_t)2048 * 256 * 2);
    u16*   A_p   = (u16*)take((size_t)2048 * 256 * 2);
    u16*   WcTe  = (u16*)take((size_t)128 * 256 * 2);
    u16*   WcTp  = (u16*)take((size_t)128 * 256 * 2);
    u16*   W1T   = (u16*)take((size_t)128 * 128 * 2);
    u16*   W2T   = (u16*)take((size_t)128 * 128 * 2);
    u16*   b_e   = (u16*)take(256);
    u16*   b_p   = (u16*)take(256);
    u16*   h_e   = (u16*)take((size_t)2048 * 128 * 2);
    u16*   h_p   = (u16*)take((size_t)2048 * 128 * 2);
    float* esum_d = (float*)take(128 * 4);
    float* esum_p = (float*)take(128 * 4);
    float* part  = (float*)take(64 * 4);
    u16*   canon = (u16*)take((size_t)700000 * 2);
    u32*   flag  = (u32*)take(256);
    u16* X  = Xbuf;
    u16* X1 = Xbuf + (size_t)BB * 128;
    u16* X2 = epT;   // epT dead after sagg

    // -------- canonical parameter table --------
    const int segidx[NSEG] = {6, 7, 14, 18, 8, 22, 11, 24, 26, 28,
                              15, 16, 17, 19, 20, 21,
                              9, 10, 12, 13, 23, 25, 27, 29, 30, 31};
    const int segn[NSEG]   = {262144, 262144, 8192, 8192, 16384, 16384, 16384, 16384, 16384, 16384,
                              32, 32, 1, 32, 32, 1,
                              128, 128, 128, 128, 128, 128, 128, 128, 128, 1};
    CvtArgs ca;
    u16* cp[NSEG];
    {
        int o = 0;
        for (int i = 0; i < NSEG; i++) {
            ca.src[i] = d_in[segidx[i]];
            ca.off[i] = o;
            ca.n[i] = segn[i];
            cp[i] = canon + o;
            o += (segn[i] + 15) & ~15;
        }
    }
    u16 *cdemb = cp[0], *cpemb = cp[1], *cWa1d = cp[2], *cWa1p = cp[3];
    u16 *cWdg = cp[4], *cWd2 = cp[5], *cWpg = cp[6], *cWp3 = cp[7];
    u16 *cW1 = cp[8], *cW2 = cp[9];
    u16 *cba1d = cp[10], *cWa2d = cp[11], *cba2d = cp[12];
    u16 *cba1p = cp[13], *cWa2p = cp[14], *cba2p = cp[15];
    u16 *cbdg_lin = cp[16], *cbdg = cp[17], *cbpg_lin = cp[18], *cbpg = cp[19];
    u16 *cbd2 = cp[20], *cbp3 = cp[21], *cmb1 = cp[22], *cmb2 = cp[23];
    u16 *cWpred = cp[24], *cbpred = cp[25];

    // -------- 0. dtype detection + canonicalization --------
    detectk<<<1, 256, 0, stream>>>(d_in[6], flag);
    cvtk<<<dim3(64, NSEG), 256, 0, stream>>>(ca, canon, flag);

    // -------- 1. prep --------
    tpose_smalls<<<dim3(4, 4, 6), dim3(32, 8), 0, stream>>>(
        cW1, cW2, cWdg, cWd2, cWpg, cWp3, W1T, W2T, WcTe, WcTp);
    biasc<<<1, 128, 0, stream>>>(cbdg_lin, cbdg, cbd2, b_e, cbpg_lin, cbpg, cbp3, b_p);
    tposeEP<<<dim3(64, 64), dim3(32, 8), 0, stream>>>(e_p_adj, epT, flag);
    embsumk<<<2, 1024, 0, stream>>>(cdemb, cpemb, esum_d, esum_p);
    koqs<<<dim3(2048, 4), 128, 0, stream>>>(cdemb, cpemb, cWa1d, cba1d, cWa1p, cba1p,
                                            ko_d, qs_d, ko_p, qs_p);

    // -------- 2. sparse fused attention + knn aggregation (one launch) ------
    {
        SG s;
        s.adj[0] = e_p_adj; s.adjbf[0] = 0; s.qs[0] = qs_d; s.ko[0] = ko_d;
        s.w2[0] = cWa2d; s.b2[0] = cba2d; s.embsum[0] = esum_p; s.emb[0] = cpemb;
        s.outp[0] = A_e; s.coff[0] = 0; s.mode[0] = 0;
        s.adj[1] = e_e_adj; s.adjbf[1] = 0; s.qs[1] = nullptr; s.ko[1] = nullptr;
        s.w2[1] = nullptr; s.b2[1] = nullptr; s.embsum[1] = nullptr; s.emb[1] = cdemb;
        s.outp[1] = A_e; s.coff[1] = 128; s.mode[1] = 1;
        s.adj[2] = epT; s.adjbf[2] = 1; s.qs[2] = qs_p; s.ko[2] = ko_p;
        s.w2[2] = cWa2p; s.b2[2] = cba2p; s.embsum[2] = esum_d; s.emb[2] = cdemb;
        s.outp[2] = A_p; s.coff[2] = 0; s.mode[2] = 0;
        s.adj[3] = p_p_adj; s.adjbf[3] = 0; s.qs[3] = nullptr; s.ko[3] = nullptr;
        s.w2[3] = nullptr; s.b2[3] = nullptr; s.embsum[3] = nullptr; s.emb[3] = cpemb;
        s.outp[3] = A_p; s.coff[3] = 128; s.mode[3] = 1;
        sagg2<<<dim3(2048, 4), 512, 0, stream>>>(s, flag);
    }

    auto setd = [](GD4& g, int z, const void* A, int lda, const u16* BT, int ldb,
                   u16* C, int ldc, int coff, int ki, const u16* bi,
                   const float* rs, int act, int araw, int rm) {
        g.A[z] = A; g.lda[z] = lda; g.BT[z] = BT; g.ldb[z] = ldb;
        g.C[z] = C; g.ldc[z] = ldc; g.coff[z] = coff; g.kiters[z] = ki;
        g.bias[z] = bi; g.rs[z] = rs; g.act[z] = act; g.araw[z] = araw; g.rsmode[z] = rm;
    };

    // -------- 3. combine GEMMs (bias + SELU), batched ----------------------
    {
        GD4 g;
        setd(g, 0, A_e, 256, WcTe, 256, h_e, 128, 0, 2, b_e, nullptr, 1, 0, 0);
        setd(g, 1, A_p, 256, WcTp, 256, h_p, 128, 0, 2, b_p, nullptr, 1, 0, 0);
        setd(g, 2, A_e, 256, WcTe, 256, h_e, 128, 0, 2, b_e, nullptr, 1, 0, 0);
        setd(g, 3, A_e, 256, WcTe, 256, h_e, 128, 0, 2, b_e, nullptr, 1, 0, 0);
        gemmL<<<dim3(128, 2), 256, 0, stream>>>(g, flag);
    }

    // -------- 4. pair MLP --------
    xbuild<<<4096, 256, 0, stream>>>(h_e, h_p, in_dis, in_drug, X);
    {
        GD4 g;
        setd(g, 0, X, 128, W1T, 128, X1, 128, 0, 1, cmb1, nullptr, 1, 0, 0);
        setd(g, 1, X, 128, W1T, 128, X1, 128, 0, 1, cmb1, nullptr, 1, 0, 0);
        setd(g, 2, X, 128, W1T, 128, X1, 128, 0, 1, cmb1, nullptr, 1, 0, 0);
        setd(g, 3, X, 128, W1T, 128, X1, 128, 0, 1, cmb1, nullptr, 1, 0, 0);
        gemmL<<<dim3(1024, 1), 256, 0, stream>>>(g, flag);
    }
    {
        GD4 g;
        setd(g, 0, X1, 128, W2T, 128, X2, 128, 0, 1, cmb2, nullptr, 1, 0, 0);
        setd(g, 1, X1, 128, W2T, 128, X2, 128, 0, 1, cmb2, nullptr, 1, 0, 0);
        setd(g, 2, X1, 128, W2T, 128, X2, 128, 0, 1, cmb2, nullptr, 1, 0, 0);
        setd(g, 3, X1, 128, W2T, 128, X2, 128, 0, 1, cmb2, nullptr, 1, 0, 0);
        gemmL<<<dim3(1024, 1), 256, 0, stream>>>(g, flag);
    }

    // -------- 5. z / sigmoid / loss --------
    zloss<<<64, 256, 0, stream>>>(X2, cWpred, cbpred, labels, out, part);
    finloss<<<1, 64, 0, stream>>>(part, out);
}